// Round 6
// baseline (1506.293 us; speedup 1.0000x reference)
//
#include <hip/hip_runtime.h>
#include <hip/hip_bf16.h>
#include <math.h>

typedef __hip_bfloat16 bf16;
typedef unsigned short u16;
typedef __attribute__((ext_vector_type(8))) short short8;
typedef __attribute__((ext_vector_type(4))) float f32x4;

#define PP 1024
#define LL 32
#define EE 512
#define DD 768
#define NLAYER 6
#define FFDIM 3072

__device__ __forceinline__ float bf2f(u16 u) { return __uint_as_float(((unsigned)u) << 16); }
// fp32 -> bf16 (RNE), finite inputs only
__device__ __forceinline__ u16 f2b(float x) {
  unsigned u = __float_as_uint(x);
  return (u16)((u + 0x7FFFu + ((u >> 16) & 1u)) >> 16);
}

// ---------------------------------------------------------------------------
// 4-region fp32 -> bf16 bulk convert. Region picked by blockIdx.y.
// ---------------------------------------------------------------------------
__global__ __launch_bounds__(256) void cvt4(
    const float* s0, const float* s1, const float* s2, const float* s3,
    u16* d0, u16* d1, u16* d2, u16* d3,
    int n0, int n1, int n2, int n3)
{
  int r = blockIdx.y;
  const float* s = r == 0 ? s0 : r == 1 ? s1 : r == 2 ? s2 : s3;
  u16* d        = r == 0 ? d0 : r == 1 ? d1 : r == 2 ? d2 : d3;
  int n4        = r == 0 ? n0 : r == 1 ? n1 : r == 2 ? n2 : n3;
  int i = blockIdx.x * 256 + threadIdx.x;
  if (i < n4) {
    float4 v = ((const float4*)s)[i];
    ushort4 o;
    o.x = f2b(v.x); o.y = f2b(v.y); o.z = f2b(v.z); o.w = f2b(v.w);
    ((ushort4*)d)[i] = o;
  }
}

// ---------------------------------------------------------------------------
// emb[pl][:] = (l < len[p]) ? byte_emb[tok] + local_pos[l] : 0  (fp32->bf16)
// pointers pre-offset per chunk.
// ---------------------------------------------------------------------------
__global__ __launch_bounds__(256) void embed_kernel(
    const int* __restrict__ tokens, const int* __restrict__ lengths,
    const float* __restrict__ byte_emb, const float* __restrict__ local_pos,
    bf16* __restrict__ emb)
{
  int pl = blockIdx.x;
  int p = pl >> 5, l = pl & 31;
  bool valid = l < lengths[p];
  int tok = tokens[pl];
  const float* be = byte_emb + (long)tok * EE;
  const float* lp = local_pos + (long)l * EE;
  u16* out = (u16*)emb + (long)pl * EE;
  for (int e = threadIdx.x; e < EE; e += 256) {
    float v = valid ? be[e] + lp[e] : 0.f;
    out[e] = f2b(v);
  }
}

// ---------------------------------------------------------------------------
// gemm128: C = A @ B^T (+bias). m97-structure 128x128 tile, BK=32, 4 waves,
// each wave 4x4 16x16 C-tiles (16 MFMA per K32). Single LDS buffer,
// 2 barriers per chunk. M%128==0, N%128==0, K%32==0. bf16 in, bf16/f32 out.
// ---------------------------------------------------------------------------
__global__ __launch_bounds__(256) void gemm128(
    const bf16* A, int lda, const bf16* B, int ldb,
    float* Cf, bf16* Cb, int ldc, const float* bias, int K)
{
  __shared__ u16 As[128][40];
  __shared__ u16 Bs[128][40];
  const int m0 = blockIdx.x << 7, n0 = blockIdx.y << 7;
  const int tid = threadIdx.x;
  const int wave = tid >> 6, lane = tid & 63;
  const int sr = tid >> 1;          // staging row 0..127
  const int sc = (tid & 1) << 4;    // staging col 0/16
  const u16* Ap = (const u16*)A;
  const u16* Bp = (const u16*)B;
  const int wr = (wave & 1) << 6;
  const int wc = (wave >> 1) << 6;
  const int fr = lane & 15;
  const int kq = (lane >> 4) << 3;
  f32x4 acc[4][4];
#pragma unroll
  for (int i = 0; i < 4; i++)
#pragma unroll
    for (int j = 0; j < 4; j++) acc[i][j] = (f32x4){0.f, 0.f, 0.f, 0.f};

  for (int k0 = 0; k0 < K; k0 += 32) {
    short8 a0 = *(const short8*)(Ap + (long)(m0 + sr) * lda + k0 + sc);
    short8 a1 = *(const short8*)(Ap + (long)(m0 + sr) * lda + k0 + sc + 8);
    short8 b0 = *(const short8*)(Bp + (long)(n0 + sr) * ldb + k0 + sc);
    short8 b1 = *(const short8*)(Bp + (long)(n0 + sr) * ldb + k0 + sc + 8);
    __syncthreads();   // prior reads done before overwrite
    *(short8*)&As[sr][sc] = a0;
    *(short8*)&As[sr][sc + 8] = a1;
    *(short8*)&Bs[sr][sc] = b0;
    *(short8*)&Bs[sr][sc + 8] = b1;
    __syncthreads();
    short8 af[4], bfv[4];
#pragma unroll
    for (int i = 0; i < 4; i++) af[i] = *(const short8*)&As[wr + i * 16 + fr][kq];
#pragma unroll
    for (int j = 0; j < 4; j++) bfv[j] = *(const short8*)&Bs[wc + j * 16 + fr][kq];
#pragma unroll
    for (int i = 0; i < 4; i++)
#pragma unroll
      for (int j = 0; j < 4; j++)
        acc[i][j] = __builtin_amdgcn_mfma_f32_16x16x32_bf16(af[i], bfv[j], acc[i][j], 0, 0, 0);
  }
  const int rq = (lane >> 4) << 2;
#pragma unroll
  for (int j = 0; j < 4; j++) {
    int c = n0 + wc + j * 16 + fr;
    float bvl = bias ? bias[c] : 0.f;
#pragma unroll
    for (int i = 0; i < 4; i++) {
#pragma unroll
      for (int r = 0; r < 4; r++) {
        int row = m0 + wr + i * 16 + rq + r;
        long idx = (long)row * ldc + c;
        float v = acc[i][j][r] + bvl;
        if (Cf) Cf[idx] = v;
        if (Cb) Cb[idx] = __float2bfloat16(v);
      }
    }
  }
}

// ---------------------------------------------------------------------------
// gemm64: C = A @ B^T (+bias)(+addf)(gelu). bf16 in, fp32 acc. 64x64 tile,
// BK=64, double-buffered LDS, loads overlap MFMA. blockIdx.x = m-tile.
// M%64==0; N,K guarded. Batched via blockIdx.z.
// ---------------------------------------------------------------------------
__global__ __launch_bounds__(256) void gemm64(
    const bf16* A, long sAb, int lda,
    const bf16* B, long sBb, int ldb,
    float* Cf, bf16* Cb, long sCb, int ldc,
    const float* bias, int biasStride,
    const float* addf,
    int M, int N, int K, int act)
{
  __shared__ u16 As[2][64][72];
  __shared__ u16 Bs[2][64][72];
  const int bz = blockIdx.z;
  const u16* Ap = (const u16*)A + (long)bz * sAb;
  const u16* Bp = (const u16*)B + (long)bz * sBb;
  const long coff = (long)bz * sCb;
  const int m0 = blockIdx.x << 6, n0 = blockIdx.y << 6;
  const int tid = threadIdx.x;
  const int wave = tid >> 6, lane = tid & 63;
  const int sr = tid >> 3;
  const int scc = (tid & 7) << 3;
  const int br0 = n0 + sr, br1 = n0 + sr + 32;
  const short8 zz = {0,0,0,0,0,0,0,0};
  f32x4 acc[4] = {{0.f,0.f,0.f,0.f},{0.f,0.f,0.f,0.f},{0.f,0.f,0.f,0.f},{0.f,0.f,0.f,0.f}};

  {
    int ch = K < 64 ? K : 64;
    bool kv = scc < ch;
    short8 a0 = zz, a1 = zz, b0 = zz, b1 = zz;
    if (kv) {
      a0 = *(const short8*)(Ap + (long)(m0 + sr) * lda + scc);
      a1 = *(const short8*)(Ap + (long)(m0 + sr + 32) * lda + scc);
      if (br0 < N) b0 = *(const short8*)(Bp + (long)br0 * ldb + scc);
      if (br1 < N) b1 = *(const short8*)(Bp + (long)br1 * ldb + scc);
    }
    *(short8*)&As[0][sr][scc] = a0;
    *(short8*)&As[0][sr + 32][scc] = a1;
    *(short8*)&Bs[0][sr][scc] = b0;
    *(short8*)&Bs[0][sr + 32][scc] = b1;
  }
  __syncthreads();

  const int arow = (wave << 4) + (lane & 15);
  const int kq = (lane >> 4) << 3;
  int buf = 0;
  for (int k0 = 0; k0 < K; k0 += 64) {
    int knext = k0 + 64;
    bool more = knext < K;
    short8 a0 = zz, a1 = zz, b0 = zz, b1 = zz;
    if (more) {
      int ch = K - knext; if (ch > 64) ch = 64;
      bool kv = scc < ch;
      if (kv) {
        a0 = *(const short8*)(Ap + (long)(m0 + sr) * lda + knext + scc);
        a1 = *(const short8*)(Ap + (long)(m0 + sr + 32) * lda + knext + scc);
        if (br0 < N) b0 = *(const short8*)(Bp + (long)br0 * ldb + knext + scc);
        if (br1 < N) b1 = *(const short8*)(Bp + (long)br1 * ldb + knext + scc);
      }
    }
    int rem = K - k0; if (rem > 64) rem = 64;
    {
      short8 af = *(const short8*)&As[buf][arow][kq];
#pragma unroll
      for (int nt = 0; nt < 4; nt++) {
        short8 bfr = *(const short8*)&Bs[buf][(nt << 4) + (lane & 15)][kq];
        acc[nt] = __builtin_amdgcn_mfma_f32_16x16x32_bf16(af, bfr, acc[nt], 0, 0, 0);
      }
    }
    if (rem > 32) {
      short8 af = *(const short8*)&As[buf][arow][32 + kq];
#pragma unroll
      for (int nt = 0; nt < 4; nt++) {
        short8 bfr = *(const short8*)&Bs[buf][(nt << 4) + (lane & 15)][32 + kq];
        acc[nt] = __builtin_amdgcn_mfma_f32_16x16x32_bf16(af, bfr, acc[nt], 0, 0, 0);
      }
    }
    if (more) {
      int nb = buf ^ 1;
      *(short8*)&As[nb][sr][scc] = a0;
      *(short8*)&As[nb][sr + 32][scc] = a1;
      *(short8*)&Bs[nb][sr][scc] = b0;
      *(short8*)&Bs[nb][sr + 32][scc] = b1;
      __syncthreads();
      buf = nb;
    }
  }

  int rbase = m0 + (wave << 4) + ((lane >> 4) << 2);
#pragma unroll
  for (int nt = 0; nt < 4; nt++) {
    int c = n0 + (nt << 4) + (lane & 15);
    if (c >= N) continue;
    float bvl = bias ? bias[bz * biasStride + c] : 0.f;
#pragma unroll
    for (int j = 0; j < 4; j++) {
      int r = rbase + j;
      long idx = coff + (long)r * ldc + c;
      float v = acc[nt][j] + bvl;
      if (addf) v += addf[idx];
      if (act == 1) v = 0.5f * v * (1.f + erff(v * 0.70710678118654752f));
      if (Cf) Cf[idx] = v;
      if (Cb) Cb[idx] = __float2bfloat16(v);
    }
  }
}

// ---------------------------------------------------------------------------
// Flash attention for the transformer layers (8 heads, d=96, S=1024).
// Block = (q-tile of 64 rows) x head; wave owns 16 q-rows. QK^T via MFMA with
// fragments loaded directly from global (qkvt rows are K-contiguous).
// Online softmax in MFMA C-layout (shfl_xor row reductions). P goes
// C-layout -> A-layout through a per-wave double-buffered LDS tile.
// PV uses pre-transposed Vt [768,1024].
// ---------------------------------------------------------------------------
__global__ __launch_bounds__(256) void attn_flash(
    const bf16* __restrict__ qkvt,   // [1024,2304] (Q|K|V)
    const bf16* __restrict__ Vt,     // [768,1024]
    bf16* __restrict__ attn)         // [1024,768]
{
  __shared__ u16 Pls[2][4][16][64];
  const int q0 = blockIdx.x << 6;
  const int h = blockIdx.y;
  const int tid = threadIdx.x, wave = tid >> 6, lane = tid & 63;
  const u16* qp = (const u16*)qkvt;
  const u16* vp = (const u16*)Vt + (long)h * 96 * 1024;
  const int fr = lane & 15;
  const int kq = (lane >> 4) << 3;
  const int rq = (lane >> 4) << 2;
  const int qrow = q0 + wave * 16 + fr;
  short8 qf[3];
#pragma unroll
  for (int c = 0; c < 3; c++)
    qf[c] = *(const short8*)(qp + (long)qrow * 2304 + h * 96 + c * 32 + kq);
  f32x4 O[6];
#pragma unroll
  for (int ct = 0; ct < 6; ct++) O[ct] = (f32x4){0.f, 0.f, 0.f, 0.f};
  float mrun[4] = {-1e30f, -1e30f, -1e30f, -1e30f};
  float lrun[4] = {0.f, 0.f, 0.f, 0.f};
  const float scale = 0.10206207261596577f;  // 96^-0.5

  for (int kt = 0; kt < 16; kt++) {
    const int k0 = kt << 6;
    f32x4 S[4];
#pragma unroll
    for (int j = 0; j < 4; j++) S[j] = (f32x4){0.f, 0.f, 0.f, 0.f};
#pragma unroll
    for (int c = 0; c < 3; c++) {
#pragma unroll
      for (int j = 0; j < 4; j++) {
        short8 kf = *(const short8*)(qp + (long)(k0 + j * 16 + fr) * 2304 + 768 + h * 96 + c * 32 + kq);
        S[j] = __builtin_amdgcn_mfma_f32_16x16x32_bf16(qf[c], kf, S[j], 0, 0, 0);
      }
    }
    float mx[4];
#pragma unroll
    for (int r = 0; r < 4; r++) {
      float m = -1e30f;
#pragma unroll
      for (int j = 0; j < 4; j++) { S[j][r] *= scale; m = fmaxf(m, S[j][r]); }
      mx[r] = m;
    }
#pragma unroll
    for (int d = 1; d < 16; d <<= 1)
#pragma unroll
      for (int r = 0; r < 4; r++) mx[r] = fmaxf(mx[r], __shfl_xor(mx[r], d));
    float alpha[4];
#pragma unroll
    for (int r = 0; r < 4; r++) {
      float mn = fmaxf(mrun[r], mx[r]);
      alpha[r] = __expf(mrun[r] - mn);
      mrun[r] = mn;
    }
    float rs[4] = {0.f, 0.f, 0.f, 0.f};
#pragma unroll
    for (int j = 0; j < 4; j++)
#pragma unroll
      for (int r = 0; r < 4; r++) {
        float e = __expf(S[j][r] - mrun[r]);
        S[j][r] = e;
        rs[r] += e;
      }
#pragma unroll
    for (int d = 1; d < 16; d <<= 1)
#pragma unroll
      for (int r = 0; r < 4; r++) rs[r] += __shfl_xor(rs[r], d);
#pragma unroll
    for (int r = 0; r < 4; r++) lrun[r] = lrun[r] * alpha[r] + rs[r];
#pragma unroll
    for (int ct = 0; ct < 6; ct++)
#pragma unroll
      for (int r = 0; r < 4; r++) O[ct][r] *= alpha[r];
    // P: C-layout -> LDS (per-wave tile, double-buffered by kt parity)
    const int pb = kt & 1;
#pragma unroll
    for (int j = 0; j < 4; j++)
#pragma unroll
      for (int r = 0; r < 4; r++)
        Pls[pb][wave][rq + r][j * 16 + fr] = f2b(S[j][r]);
    __syncthreads();
    // PV
#pragma unroll
    for (int kc = 0; kc < 2; kc++) {
      short8 pa = *(const short8*)&Pls[pb][wave][fr][kc * 32 + kq];
#pragma unroll
      for (int ct = 0; ct < 6; ct++) {
        short8 vf = *(const short8*)(vp + (long)(ct * 16 + fr) * 1024 + k0 + kc * 32 + kq);
        O[ct] = __builtin_amdgcn_mfma_f32_16x16x32_bf16(pa, vf, O[ct], 0, 0, 0);
      }
    }
  }
  u16* op = (u16*)attn;
#pragma unroll
  for (int r = 0; r < 4; r++) {
    float inv = 1.f / lrun[r];
    int row = q0 + wave * 16 + rq + r;
#pragma unroll
    for (int ct = 0; ct < 6; ct++)
      op[(long)row * 768 + h * 96 + ct * 16 + fr] = f2b(O[ct][r] * inv);
  }
}

// ---------------------------------------------------------------------------
// Per-patch MHA over 32 bytes (4 heads, d=128) fused with masked mean.
// MFMA QK^T direct from global; softmax + column-mean via shuffle in C-layout.
// V path commuted: z_h = wsum_h @ emb. Pointers pre-offset per chunk.
// ---------------------------------------------------------------------------
__global__ __launch_bounds__(256) void patch_attn(
    const bf16* __restrict__ qk,   // chunk-local [8192, 1024] = [Q|K]
    const int* __restrict__ tokens, const int* __restrict__ lengths,
    const float* __restrict__ byte_emb, const float* __restrict__ local_pos,
    bf16* __restrict__ Z)          // chunk-local [256, 4, 512]
{
  __shared__ float wsum[4][32];
  __shared__ int tok_s[32];
  __shared__ int cnt_s;
  int p = blockIdx.x;
  int tid = threadIdx.x;
  if (tid < 32) tok_s[tid] = tokens[p * 32 + tid];
  if (tid == 0) cnt_s = lengths[p];
  __syncthreads();
  int cnt = cnt_s;
  int h = tid >> 6, lane = tid & 63;
  const u16* base = (const u16*)qk + (long)p * 32 * 1024 + h * 128;
  const int rsel = lane & 15;
  const int ksel = (lane >> 4) << 3;

  f32x4 acc[2][2] = {{{0.f,0.f,0.f,0.f},{0.f,0.f,0.f,0.f}},
                     {{0.f,0.f,0.f,0.f},{0.f,0.f,0.f,0.f}}};
#pragma unroll
  for (int kc = 0; kc < 4; kc++) {
    int ko = kc * 32 + ksel;
    short8 a0 = *(const short8*)(base + (long)rsel * 1024 + ko);
    short8 a1 = *(const short8*)(base + (long)(16 + rsel) * 1024 + ko);
    short8 b0 = *(const short8*)(base + 512 + (long)rsel * 1024 + ko);
    short8 b1 = *(const short8*)(base + 512 + (long)(16 + rsel) * 1024 + ko);
    acc[0][0] = __builtin_amdgcn_mfma_f32_16x16x32_bf16(a0, b0, acc[0][0], 0, 0, 0);
    acc[0][1] = __builtin_amdgcn_mfma_f32_16x16x32_bf16(a0, b1, acc[0][1], 0, 0, 0);
    acc[1][0] = __builtin_amdgcn_mfma_f32_16x16x32_bf16(a1, b0, acc[1][0], 0, 0, 0);
    acc[1][1] = __builtin_amdgcn_mfma_f32_16x16x32_bf16(a1, b1, acc[1][1], 0, 0, 0);
  }

  const float scale = 0.088388347648318447f;  // 128^-0.5
  int j0 = lane & 15, j1 = 16 + j0;
  bool v0 = j0 < cnt, v1 = j1 < cnt;
  int rowq = (lane >> 4) << 2;
  float cs0 = 0.f, cs1 = 0.f;
#pragma unroll
  for (int ti = 0; ti < 2; ti++) {
    float s0[4], s1[4], mx[4], sm[4], e0[4], e1[4];
#pragma unroll
    for (int r = 0; r < 4; r++) {
      s0[r] = acc[ti][0][r] * scale;
      s1[r] = acc[ti][1][r] * scale;
      float a = v0 ? s0[r] : -1e30f;
      float b = v1 ? s1[r] : -1e30f;
      mx[r] = fmaxf(a, b);
    }
#pragma unroll
    for (int d = 1; d < 16; d <<= 1)
#pragma unroll
      for (int r = 0; r < 4; r++) mx[r] = fmaxf(mx[r], __shfl_xor(mx[r], d));
#pragma unroll
    for (int r = 0; r < 4; r++) {
      e0[r] = v0 ? __expf(s0[r] - mx[r]) : 0.f;
      e1[r] = v1 ? __expf(s1[r] - mx[r]) : 0.f;
      sm[r] = e0[r] + e1[r];
    }
#pragma unroll
    for (int d = 1; d < 16; d <<= 1)
#pragma unroll
      for (int r = 0; r < 4; r++) sm[r] += __shfl_xor(sm[r], d);
#pragma unroll
    for (int r = 0; r < 4; r++) {
      int row = ti * 16 + rowq + r;
      if (row < cnt) {
        float inv = 1.f / sm[r];
        cs0 += e0[r] * inv;
        cs1 += e1[r] * inv;
      }
    }
  }
  cs0 += __shfl_xor(cs0, 16); cs0 += __shfl_xor(cs0, 32);
  cs1 += __shfl_xor(cs1, 16); cs1 += __shfl_xor(cs1, 32);
  if (lane < 16) {
    float invc = 1.f / (float)cnt;
    wsum[h][lane] = cs0 * invc;
    wsum[h][16 + lane] = cs1 * invc;
  }
  __syncthreads();

  for (int e = tid; e < 512; e += 256) {
    float za0 = 0.f, za1 = 0.f, za2 = 0.f, za3 = 0.f;
    for (int j = 0; j < cnt; j++) {
      float ev = byte_emb[((long)tok_s[j] << 9) + e] + local_pos[((long)j << 9) + e];
      za0 += wsum[0][j] * ev;
      za1 += wsum[1][j] * ev;
      za2 += wsum[2][j] * ev;
      za3 += wsum[3][j] * ev;
    }
    long zb = (long)p * 2048;
    Z[zb + e]        = __float2bfloat16(za0);
    Z[zb + 512 + e]  = __float2bfloat16(za1);
    Z[zb + 1024 + e] = __float2bfloat16(za2);
    Z[zb + 1536 + e] = __float2bfloat16(za3);
  }
}

// ---------------------------------------------------------------------------
// Row LayerNorm: fp32 in, fp32 w/b; bf16 out (outb) or fp32 out (outf).
// ---------------------------------------------------------------------------
__global__ __launch_bounds__(256) void ln_kernel(
    const float* __restrict__ x, const float* __restrict__ w, const float* __restrict__ b,
    bf16* outb, float* outf, int N)
{
  __shared__ float red[8];
  __shared__ float mv[2];
  int row = blockIdx.x;
  const float* xr = x + (long)row * N;
  int tid = threadIdx.x, lane = tid & 63, wave = tid >> 6;
  float s = 0.f, s2 = 0.f;
  for (int c = tid; c < N; c += 256) { float v = xr[c]; s += v; s2 += v * v; }
  for (int o = 32; o; o >>= 1) { s += __shfl_down(s, o); s2 += __shfl_down(s2, o); }
  if (lane == 0) { red[wave] = s; red[4 + wave] = s2; }
  __syncthreads();
  if (tid == 0) {
    float ts = red[0] + red[1] + red[2] + red[3];
    float ts2 = red[4] + red[5] + red[6] + red[7];
    float mu = ts / N;
    float var = ts2 / N - mu * mu;
    mv[0] = mu; mv[1] = rsqrtf(var + 1e-5f);
  }
  __syncthreads();
  float mu = mv[0], rstd = mv[1];
  for (int c = tid; c < N; c += 256) {
    float v = (xr[c] - mu) * rstd * w[c] + b[c];
    if (outb) outb[(long)row * N + c] = __float2bfloat16(v);
    if (outf) outf[(long)row * N + c] = v;
  }
}

// ---------------------------------------------------------------------------
// Vt[d][k] = qkv[k][1536 + d]  (V part), 32x32 LDS tiles. bf16.
// ---------------------------------------------------------------------------
__global__ __launch_bounds__(256) void transpose_v(
    const bf16* __restrict__ qkv, bf16* __restrict__ Vt)
{
  __shared__ u16 tile[32][33];
  int k0 = blockIdx.x << 5;
  int d0 = blockIdx.y << 5;
  int tx = threadIdx.x & 31, ty = threadIdx.x >> 5;
  const u16* q = (const u16*)qkv;
  for (int i = ty; i < 32; i += 8)
    tile[i][tx] = q[(long)(k0 + i) * 2304 + 1536 + d0 + tx];
  __syncthreads();
  u16* vt = (u16*)Vt;
  for (int i = ty; i < 32; i += 8)
    vt[(long)(d0 + i) * 1024 + k0 + tx] = tile[tx][i];
}

extern "C" void kernel_launch(void* const* d_in, const int* in_sizes, int n_in,
                              void* d_out, int out_size, void* d_ws, size_t ws_size,
                              hipStream_t stream)
{
  const int*   tokens    = (const int*)d_in[0];
  const int*   lengths   = (const int*)d_in[1];
  const float* byte_emb  = (const float*)d_in[2];
  const float* local_pos = (const float*)d_in[3];
  const float* patch_pos = (const float*)d_in[4];
  const float* pa_qkv_w  = (const float*)d_in[5];
  const float* pa_qkv_b  = (const float*)d_in[6];
  const float* pa_out_w  = (const float*)d_in[7];
  const float* pa_out_b  = (const float*)d_in[8];
  const float* proj_w    = (const float*)d_in[9];
  const float* proj_b    = (const float*)d_in[10];
  const float* Wqkv      = (const float*)d_in[11];
  const float* Bqkv      = (const float*)d_in[12];
  const float* Wout      = (const float*)d_in[13];
  const float* Bout      = (const float*)d_in[14];
  const float* ln1w      = (const float*)d_in[15];
  const float* ln1b      = (const float*)d_in[16];
  const float* ln2w      = (const float*)d_in[17];
  const float* ln2b      = (const float*)d_in[18];
  const float* W1        = (const float*)d_in[19];
  const float* B1        = (const float*)d_in[20];
  const float* W2        = (const float*)d_in[21];
  const float* B2        = (const float*)d_in[22];
  const float* lnfw      = (const float*)d_in[23];
  const float* lnfb      = (const float*)d_in[24];

  char* ws = (char*)d_ws;
  const size_t MB = 1ull << 20;
  // ---- layout (67 MB total; proven budget >= 82 MB) ----
  bf16* QKC    = (bf16*)(ws);              // [0,16)  phase1 chunk [8192,1024]
  bf16* embC   = (bf16*)(ws + 16 * MB);    // [16,24) phase1 chunk [8192,512]
  bf16* Z      = (bf16*)(ws + 24 * MB);    // [24,28) [1024,4,512]
  bf16* o_mean = (bf16*)(ws + 28 * MB);    // [28,29)
  bf16* t1     = (bf16*)(ws + 29 * MB);    // [29,30)
  u16*  P1w    = (u16*)(ws + 30 * MB);     // [30,33) phase1 bf16 weights
  float* h     = (float*)(ws + 33 * MB);   // [33,36) [1024,768] fp32
  bf16* hn     = (bf16*)(ws + 36 * MB);    // [36,38)
  bf16* qkvt   = (bf16*)(ws + 38 * MB);    // [38,43) [1024,2304]
  bf16* Vt     = (bf16*)(ws + 43 * MB);    // [43,45) [768,1024]
  bf16* attn   = (bf16*)(ws + 45 * MB);    // [45,47) [1024,768]
  bf16* ffb    = (bf16*)(ws + 47 * MB);    // [47,53) [1024,3072]
  u16*  Lw     = (u16*)(ws + 53 * MB);     // [53,67) per-layer bf16 weights

  const long oLQKV = 0;          // [2304,768]
  const long oLOUT = 1769472;    // [768,768]
  const long oLW1  = 2359296;    // [3072,768]
  const long oLW2  = 4718592;    // [768,3072]
  const long oPAQ  = 0;          // [1536,512]
  const long oPAO  = 786432;     // [512,512]
  const long oPRJ  = 1048576;    // [768,512]

  // ---- phase 1: patch encoder, 4 chunks of 256 patches ----
  cvt4<<<dim3(768, 3), 256, 0, stream>>>(
      pa_qkv_w, pa_out_w, proj_w, nullptr,
      P1w + oPAQ, P1w + oPAO, P1w + oPRJ, nullptr,
      786432 / 4, 262144 / 4, 393216 / 4, 0);
  for (int c = 0; c < 4; c++) {
    int p0 = c * 256, row0 = c * 8192;
    embed_kernel<<<8192, 256, 0, stream>>>(
        tokens + row0, lengths + p0, byte_emb, local_pos, embC);
    // QKC = embC @ Wqk^T + bqk  [8192,1024]
    gemm128<<<dim3(64, 8), 256, 0, stream>>>(
        embC, EE, (bf16*)(P1w + oPAQ), EE, nullptr, QKC, 1024, pa_qkv_b, EE);
    patch_attn<<<256, 256, 0, stream>>>(
        QKC, tokens + row0, lengths + p0, byte_emb, local_pos, Z + (long)p0 * 2048);
  }
  // o_mean[:, h*128:(h+1)*128] = Z[:,h,:] @ Wv_h^T + bv_h
  gemm64<<<dim3(16, 2, 4), 256, 0, stream>>>(
      Z, 512, 2048, (bf16*)(P1w + oPAQ + 1024L * EE), 128L * EE, EE,
      nullptr, o_mean, 128, EE, pa_qkv_b + 1024, 128, nullptr, PP, 128, EE, 0);
  // t1 = o_mean @ pa_out_w^T + b
  gemm64<<<dim3(16, 8, 1), 256, 0, stream>>>(
      o_mean, 0, EE, (bf16*)(P1w + oPAO), 0, EE, nullptr, t1, 0, EE,
      pa_out_b, 0, nullptr, PP, EE, EE, 0);
  // h = t1 @ proj_w^T + b + patch_pos (fp32)
  gemm64<<<dim3(16, 12, 1), 256, 0, stream>>>(
      t1, 0, EE, (bf16*)(P1w + oPRJ), 0, EE, h, nullptr, 0, DD,
      proj_b, 0, patch_pos, PP, DD, EE, 0);

  // ---- phase 2: transformer encoder ----
  for (int i = 0; i < NLAYER; i++) {
    cvt4<<<dim3(2304, 4), 256, 0, stream>>>(
        Wqkv + (long)i * 2304 * DD, Wout + (long)i * DD * DD,
        W1 + (long)i * FFDIM * DD, W2 + (long)i * DD * FFDIM,
        Lw + oLQKV, Lw + oLOUT, Lw + oLW1, Lw + oLW2,
        1769472 / 4, 589824 / 4, 2359296 / 4, 2359296 / 4);
    ln_kernel<<<PP, 256, 0, stream>>>(h, ln1w + i * DD, ln1b + i * DD, hn, nullptr, DD);
    gemm64<<<dim3(16, 36, 1), 256, 0, stream>>>(
        hn, 0, DD, (bf16*)(Lw + oLQKV), 0, DD, nullptr, qkvt, 0, 2304,
        Bqkv + i * 2304, 0, nullptr, PP, 2304, DD, 0);
    transpose_v<<<dim3(32, 24), 256, 0, stream>>>(qkvt, Vt);
    attn_flash<<<dim3(16, 8), 256, 0, stream>>>(qkvt, Vt, attn);
    // h += attn @ Wout^T + bo
    gemm64<<<dim3(16, 12, 1), 256, 0, stream>>>(
        attn, 0, DD, (bf16*)(Lw + oLOUT), 0, DD, h, nullptr, 0, DD,
        Bout + i * DD, 0, h, PP, DD, DD, 0);
    ln_kernel<<<PP, 256, 0, stream>>>(h, ln2w + i * DD, ln2b + i * DD, hn, nullptr, DD);
    // ffb = gelu(hn @ W1^T + b1)
    gemm64<<<dim3(16, 48, 1), 256, 0, stream>>>(
        hn, 0, DD, (bf16*)(Lw + oLW1), 0, DD, nullptr, ffb, 0, FFDIM,
        B1 + i * FFDIM, 0, nullptr, PP, FFDIM, DD, 1);
    // h += ffb @ W2^T + b2
    gemm64<<<dim3(16, 12, 1), 256, 0, stream>>>(
        ffb, 0, FFDIM, (bf16*)(Lw + oLW2), 0, FFDIM, h, nullptr, 0, DD,
        B2 + i * DD, 0, h, PP, DD, FFDIM, 0);
  }
  ln_kernel<<<PP, 256, 0, stream>>>(h, lnfw, lnfb, nullptr, (float*)d_out, DD);
}